// Round 3
// baseline (117.827 us; speedup 1.0000x reference)
//
#include <hip/hip_runtime.h>
#include <math.h>

#define N_ROWS 2048
#define D_DIM 512
#define P_DIM 10

__device__ inline float wave_reduce_f(float v) {
#pragma unroll
  for (int off = 32; off > 0; off >>= 1) v += __shfl_down(v, off, 64);
  return v;
}

__device__ inline double wave_reduce_d(double v) {
#pragma unroll
  for (int off = 32; off > 0; off >>= 1) v += __shfl_down(v, off, 64);
  return v;
}

// Monotone float32 -> u32 map (ascending), with row index in the low 32 bits
// as a stable-sort tiebreak -> all 2048 keys per column are UNIQUE, so
// rank = #{keys < mine} is an exact permutation matching jnp.sort.
__device__ inline unsigned long long sort_key(float v, int idx) {
  unsigned u = __float_as_uint(v);
  unsigned s = (u & 0x80000000u) ? ~u : (u | 0x80000000u);
  return ((unsigned long long)s << 32) | (unsigned)idx;
}

// K1: wave-per-row projection. Emits sort keys directly:
// keys[p][row]        = key(z[row,:]@proj[:,p], row)
// keys[10+p][row]     = key((g[row,:]/max(||g||,eps))@proj[:,p], row)
// Block 0 zeroes d_out (harness poisons it to 0xAA before every timed call;
// K3 accumulates into it with atomics).
__global__ __launch_bounds__(256) void rc_proj_kernel(
    const float4* __restrict__ z4, const float4* __restrict__ g4,
    const float* __restrict__ proj, unsigned long long* __restrict__ keys,
    float* __restrict__ out) {
  __shared__ float pl[P_DIM * D_DIM];  // swizzled [p][(e&3)*128 + e>>2]
  for (int i = threadIdx.x; i < P_DIM * D_DIM; i += 256) {
    int e = i / P_DIM, p = i - e * P_DIM;  // proj is [D][P] row-major
    pl[p * D_DIM + (e & 3) * 128 + (e >> 2)] = proj[i];
  }
  if (blockIdx.x == 0 && threadIdx.x == 0) out[0] = 0.f;
  __syncthreads();
  const int wave = threadIdx.x >> 6, lane = threadIdx.x & 63;
  const int row = blockIdx.x * 4 + wave;
  const float4* zr = z4 + (size_t)row * (D_DIM / 4);
  const float4* gr = g4 + (size_t)row * (D_DIM / 4);
  float4 zv[2], gv[2];
  zv[0] = zr[lane];
  zv[1] = zr[64 + lane];
  gv[0] = gr[lane];
  gv[1] = gr[64 + lane];
  float n2 = gv[0].x * gv[0].x + gv[0].y * gv[0].y + gv[0].z * gv[0].z +
             gv[0].w * gv[0].w + gv[1].x * gv[1].x + gv[1].y * gv[1].y +
             gv[1].z * gv[1].z + gv[1].w * gv[1].w;
  float az[P_DIM], ag[P_DIM];
#pragma unroll
  for (int p = 0; p < P_DIM; ++p) { az[p] = 0.f; ag[p] = 0.f; }
#pragma unroll
  for (int m = 0; m < 2; ++m) {
    const float zc[4] = {zv[m].x, zv[m].y, zv[m].z, zv[m].w};
    const float gc[4] = {gv[m].x, gv[m].y, gv[m].z, gv[m].w};
#pragma unroll
    for (int c = 0; c < 4; ++c) {
#pragma unroll
      for (int p = 0; p < P_DIM; ++p) {
        float w = pl[p * D_DIM + c * 128 + m * 64 + lane];
        az[p] += zc[c] * w;
        ag[p] += gc[c] * w;
      }
    }
  }
#pragma unroll
  for (int p = 0; p < P_DIM; ++p) {
    az[p] = wave_reduce_f(az[p]);
    ag[p] = wave_reduce_f(ag[p]);
  }
  n2 = wave_reduce_f(n2);
  if (lane == 0) {
    float inv = 1.f / fmaxf(sqrtf(n2), 1e-12f);
#pragma unroll
    for (int p = 0; p < P_DIM; ++p) {
      keys[p * N_ROWS + row] = sort_key(az[p], row);
      keys[(P_DIM + p) * N_ROWS + row] = sort_key(ag[p] * inv, row);
    }
  }
}

// K2: rank + scatter. 160 blocks (20 cols x 8 chunks) x 256 threads, one
// element per thread. No LDS, no barriers. The key stream K[j] is
// wave-uniform -> scalar/broadcast loads; 3 VALU per compared key.
// Writes sorted[col][rank] = value decoded from the key's top 32 bits.
__global__ __launch_bounds__(256) void rc_rank_kernel(
    const unsigned long long* __restrict__ keys, float* __restrict__ sorted) {
  const int col = blockIdx.x >> 3;
  const int i = ((blockIdx.x & 7) << 8) | threadIdx.x;
  const unsigned long long* __restrict__ K = keys + col * N_ROWS;
  const unsigned long long my = K[i];
  int r = 0;
#pragma unroll 16
  for (int j = 0; j < N_ROWS; ++j) r += (K[j] < my) ? 1 : 0;
  unsigned s = (unsigned)(my >> 32);
  unsigned u = (s & 0x80000000u) ? (s & 0x7FFFFFFFu) : ~s;
  sorted[col * N_ROWS + r] = __uint_as_float(u);
}

// Closed-form fgw from order-independent + rank-paired sums.
// s_i=a_i^2-b_i^2; gw*n^2 = 2n*Ss2 + 2*Ss^2 - 8*(Ssa*Sa - Ssb*Sb)
//                           + 4*(Sa2^2 - 2*Sab^2 + Sb2^2)
// Ss2=Sa4-2*U4+Sb4, Ss=Sa2-Sb2, Ssa=Sa3-U3, Ssb=U2-Sb3, Sab=U1;
// w = Sa2+Sb2-2*U1.
__device__ inline double fgw_eval(double Sa, double Sb, double Sa2, double Sb2,
                                  double Sa3, double Sb3, double Sa4,
                                  double Sb4, double U1, double U2, double U3,
                                  double U4) {
  const double n = (double)N_ROWS;
  double T0 = Sa4 - 2.0 * U4 + Sb4;
  double T1 = Sa2 - Sb2;
  double T2 = Sa3 - U3;
  double T4 = U2 - Sb3;
  double gw = (2.0 * n * T0 + 2.0 * T1 * T1 - 8.0 * (T2 * Sa - T4 * Sb) +
               4.0 * (Sa2 * Sa2 - 2.0 * U1 * U1 + Sb2 * Sb2)) /
              (n * n);
  double w = Sa2 + Sb2 - 2.0 * U1;
  return 0.9 * w + 0.1 * gw;
}

// K3: per-p f64 statistics over the sorted columns, both variants
// (prior2 = reversed prior1), closed-form fgw, atomicAdd(min/P) into out.
__global__ __launch_bounds__(256) void rc_stats_kernel(
    const float* __restrict__ sorted, float* __restrict__ out) {
  const int p = blockIdx.x;
  const float* a = sorted + p * N_ROWS;
  const float* b = sorted + (P_DIM + p) * N_ROWS;
  // 0:Sa 1:Sb 2:Sa2 3:Sb2 4:Sa3 5:Sb3 6:Sa4 7:Sb4
  // 8:U1 9:U2 10:U3 11:U4 (aligned)  12..15: same with b reversed
  double S[16];
#pragma unroll
  for (int t = 0; t < 16; ++t) S[t] = 0.0;
  for (int i = threadIdx.x; i < N_ROWS; i += 256) {
    double av = (double)a[i];
    double bv = (double)b[i];
    double br = (double)b[N_ROWS - 1 - i];
    double a2 = av * av, b2 = bv * bv, br2 = br * br;
    S[0] += av;
    S[1] += bv;
    S[2] += a2;
    S[3] += b2;
    S[4] += a2 * av;
    S[5] += b2 * bv;
    S[6] += a2 * a2;
    S[7] += b2 * b2;
    S[8] += av * bv;
    S[9] += a2 * bv;
    S[10] += av * b2;
    S[11] += a2 * b2;
    S[12] += av * br;
    S[13] += a2 * br;
    S[14] += av * br2;
    S[15] += a2 * br2;
  }
#pragma unroll
  for (int t = 0; t < 16; ++t) S[t] = wave_reduce_d(S[t]);
  __shared__ double sm[4][16];
  const int wave = threadIdx.x >> 6, lane = threadIdx.x & 63;
  if (lane == 0) {
#pragma unroll
    for (int t = 0; t < 16; ++t) sm[wave][t] = S[t];
  }
  __syncthreads();
  if (threadIdx.x == 0) {
    double T[16];
#pragma unroll
    for (int t = 0; t < 16; ++t)
      T[t] = sm[0][t] + sm[1][t] + sm[2][t] + sm[3][t];
    double f1 = fgw_eval(T[0], T[1], T[2], T[3], T[4], T[5], T[6], T[7], T[8],
                         T[9], T[10], T[11]);
    double f2 = fgw_eval(T[0], T[1], T[2], T[3], T[4], T[5], T[6], T[7], T[12],
                         T[13], T[14], T[15]);
    atomicAdd(out, (float)(fmin(f1, f2) * (1.0 / P_DIM)));
  }
}

extern "C" void kernel_launch(void* const* d_in, const int* in_sizes, int n_in,
                              void* d_out, int out_size, void* d_ws,
                              size_t ws_size, hipStream_t stream) {
  const float4* z4 = (const float4*)d_in[0];
  const float4* g4 = (const float4*)d_in[1];
  const float* proj = (const float*)d_in[2];
  float* out = (float*)d_out;
  unsigned long long* keys = (unsigned long long*)d_ws;  // 20*2048 u64
  float* sorted = (float*)(keys + 2 * P_DIM * N_ROWS);   // 20*2048 f32

  rc_proj_kernel<<<N_ROWS / 4, 256, 0, stream>>>(z4, g4, proj, keys, out);
  rc_rank_kernel<<<2 * P_DIM * 8, 256, 0, stream>>>(keys, sorted);
  rc_stats_kernel<<<P_DIM, 256, 0, stream>>>(sorted, out);
}

// Round 4
// 97.335 us; speedup vs baseline: 1.2105x; 1.2105x over previous
//
#include <hip/hip_runtime.h>
#include <math.h>

#define N_ROWS 2048
#define D_DIM 512
#define P_DIM 10

__device__ inline float wave_reduce_f(float v) {
#pragma unroll
  for (int off = 32; off > 0; off >>= 1) v += __shfl_down(v, off, 64);
  return v;
}

__device__ inline double wave_reduce_d(double v) {
#pragma unroll
  for (int off = 32; off > 0; off >>= 1) v += __shfl_down(v, off, 64);
  return v;
}

// Monotone float32 -> u32 map (ascending), with row index in the low 32 bits
// as a stable-sort tiebreak -> all 2048 keys per column are UNIQUE, so
// rank = #{keys < mine} is an exact permutation matching jnp.sort.
__device__ inline unsigned long long sort_key(float v, int idx) {
  unsigned u = __float_as_uint(v);
  unsigned s = (u & 0x80000000u) ? ~u : (u | 0x80000000u);
  return ((unsigned long long)s << 32) | (unsigned)idx;
}

// K1: wave-per-row projection. Emits sort keys directly:
// keys[p][row]    = key(z[row,:]@proj[:,p], row)
// keys[10+p][row] = key((g[row,:]/max(||g||,eps))@proj[:,p], row)
// Block 0 zeroes d_out (harness poisons it to 0xAA before every timed call;
// K3 accumulates into it with atomics).
__global__ __launch_bounds__(256) void rc_proj_kernel(
    const float4* __restrict__ z4, const float4* __restrict__ g4,
    const float* __restrict__ proj, unsigned long long* __restrict__ keys,
    float* __restrict__ out) {
  __shared__ float pl[P_DIM * D_DIM];  // swizzled [p][(e&3)*128 + e>>2]
  for (int i = threadIdx.x; i < P_DIM * D_DIM; i += 256) {
    int e = i / P_DIM, p = i - e * P_DIM;  // proj is [D][P] row-major
    pl[p * D_DIM + (e & 3) * 128 + (e >> 2)] = proj[i];
  }
  if (blockIdx.x == 0 && threadIdx.x == 0) out[0] = 0.f;
  __syncthreads();
  const int wave = threadIdx.x >> 6, lane = threadIdx.x & 63;
  const int row = blockIdx.x * 4 + wave;
  const float4* zr = z4 + (size_t)row * (D_DIM / 4);
  const float4* gr = g4 + (size_t)row * (D_DIM / 4);
  float4 zv[2], gv[2];
  zv[0] = zr[lane];
  zv[1] = zr[64 + lane];
  gv[0] = gr[lane];
  gv[1] = gr[64 + lane];
  float n2 = gv[0].x * gv[0].x + gv[0].y * gv[0].y + gv[0].z * gv[0].z +
             gv[0].w * gv[0].w + gv[1].x * gv[1].x + gv[1].y * gv[1].y +
             gv[1].z * gv[1].z + gv[1].w * gv[1].w;
  float az[P_DIM], ag[P_DIM];
#pragma unroll
  for (int p = 0; p < P_DIM; ++p) { az[p] = 0.f; ag[p] = 0.f; }
#pragma unroll
  for (int m = 0; m < 2; ++m) {
    const float zc[4] = {zv[m].x, zv[m].y, zv[m].z, zv[m].w};
    const float gc[4] = {gv[m].x, gv[m].y, gv[m].z, gv[m].w};
#pragma unroll
    for (int c = 0; c < 4; ++c) {
#pragma unroll
      for (int p = 0; p < P_DIM; ++p) {
        float w = pl[p * D_DIM + c * 128 + m * 64 + lane];
        az[p] += zc[c] * w;
        ag[p] += gc[c] * w;
      }
    }
  }
#pragma unroll
  for (int p = 0; p < P_DIM; ++p) {
    az[p] = wave_reduce_f(az[p]);
    ag[p] = wave_reduce_f(ag[p]);
  }
  n2 = wave_reduce_f(n2);
  if (lane == 0) {
    float inv = 1.f / fmaxf(sqrtf(n2), 1e-12f);
#pragma unroll
    for (int p = 0; p < P_DIM; ++p) {
      keys[p * N_ROWS + row] = sort_key(az[p], row);
      keys[(P_DIM + p) * N_ROWS + row] = sort_key(ag[p] * inv, row);
    }
  }
}

// K2: rank + scatter via LDS. 160 blocks = (20 cols x 8 chunks) x 256 thr.
// The whole 2048-key column is staged in LDS (16 KB, coalesced ulonglong2
// loads), then each thread ranks its one element against the column with
// wave-uniform ds_read_b128 (broadcast -> conflict-free, pipelined) —
// NOT global loads, which the compiler scalarizes into serial s_load chains
// (R3: VGPR=8/SGPR=64, 54 cyc/iter). Writes sorted[col][rank] = value.
__global__ __launch_bounds__(256) void rc_rank_kernel(
    const ulonglong2* __restrict__ keys2, float* __restrict__ sorted) {
  __shared__ ulonglong2 k2[N_ROWS / 2];  // 16 KiB
  const int col = blockIdx.x >> 3;
  const int tid = threadIdx.x;
  const ulonglong2* __restrict__ K2 = keys2 + col * (N_ROWS / 2);
#pragma unroll
  for (int t = 0; t < 4; ++t) k2[tid + 256 * t] = K2[tid + 256 * t];
  __syncthreads();
  const int i = ((blockIdx.x & 7) << 8) | tid;
  const unsigned long long my =
      ((const unsigned long long*)k2)[i];
  int r = 0;
#pragma unroll 8
  for (int j = 0; j < N_ROWS / 2; ++j) {
    ulonglong2 kk = k2[j];
    r += (kk.x < my) ? 1 : 0;
    r += (kk.y < my) ? 1 : 0;
  }
  unsigned s = (unsigned)(my >> 32);
  unsigned u = (s & 0x80000000u) ? (s & 0x7FFFFFFFu) : ~s;
  sorted[col * N_ROWS + r] = __uint_as_float(u);
}

// Closed-form fgw from order-independent + rank-paired sums.
// s_i=a_i^2-b_i^2; gw*n^2 = 2n*Ss2 + 2*Ss^2 - 8*(Ssa*Sa - Ssb*Sb)
//                           + 4*(Sa2^2 - 2*Sab^2 + Sb2^2)
// Ss2=Sa4-2*U4+Sb4, Ss=Sa2-Sb2, Ssa=Sa3-U3, Ssb=U2-Sb3, Sab=U1;
// w = Sa2+Sb2-2*U1.
__device__ inline double fgw_eval(double Sa, double Sb, double Sa2, double Sb2,
                                  double Sa3, double Sb3, double Sa4,
                                  double Sb4, double U1, double U2, double U3,
                                  double U4) {
  const double n = (double)N_ROWS;
  double T0 = Sa4 - 2.0 * U4 + Sb4;
  double T1 = Sa2 - Sb2;
  double T2 = Sa3 - U3;
  double T4 = U2 - Sb3;
  double gw = (2.0 * n * T0 + 2.0 * T1 * T1 - 8.0 * (T2 * Sa - T4 * Sb) +
               4.0 * (Sa2 * Sa2 - 2.0 * U1 * U1 + Sb2 * Sb2)) /
              (n * n);
  double w = Sa2 + Sb2 - 2.0 * U1;
  return 0.9 * w + 0.1 * gw;
}

// K3: per-p f64 statistics over the sorted columns, both variants
// (prior2 = reversed prior1), closed-form fgw, atomicAdd(min/P) into out.
__global__ __launch_bounds__(256) void rc_stats_kernel(
    const float* __restrict__ sorted, float* __restrict__ out) {
  const int p = blockIdx.x;
  const float* a = sorted + p * N_ROWS;
  const float* b = sorted + (P_DIM + p) * N_ROWS;
  // 0:Sa 1:Sb 2:Sa2 3:Sb2 4:Sa3 5:Sb3 6:Sa4 7:Sb4
  // 8:U1 9:U2 10:U3 11:U4 (aligned)  12..15: same with b reversed
  double S[16];
#pragma unroll
  for (int t = 0; t < 16; ++t) S[t] = 0.0;
  for (int i = threadIdx.x; i < N_ROWS; i += 256) {
    double av = (double)a[i];
    double bv = (double)b[i];
    double br = (double)b[N_ROWS - 1 - i];
    double a2 = av * av, b2 = bv * bv, br2 = br * br;
    S[0] += av;
    S[1] += bv;
    S[2] += a2;
    S[3] += b2;
    S[4] += a2 * av;
    S[5] += b2 * bv;
    S[6] += a2 * a2;
    S[7] += b2 * b2;
    S[8] += av * bv;
    S[9] += a2 * bv;
    S[10] += av * b2;
    S[11] += a2 * b2;
    S[12] += av * br;
    S[13] += a2 * br;
    S[14] += av * br2;
    S[15] += a2 * br2;
  }
#pragma unroll
  for (int t = 0; t < 16; ++t) S[t] = wave_reduce_d(S[t]);
  __shared__ double sm[4][16];
  const int wave = threadIdx.x >> 6, lane = threadIdx.x & 63;
  if (lane == 0) {
#pragma unroll
    for (int t = 0; t < 16; ++t) sm[wave][t] = S[t];
  }
  __syncthreads();
  if (threadIdx.x == 0) {
    double T[16];
#pragma unroll
    for (int t = 0; t < 16; ++t)
      T[t] = sm[0][t] + sm[1][t] + sm[2][t] + sm[3][t];
    double f1 = fgw_eval(T[0], T[1], T[2], T[3], T[4], T[5], T[6], T[7], T[8],
                         T[9], T[10], T[11]);
    double f2 = fgw_eval(T[0], T[1], T[2], T[3], T[4], T[5], T[6], T[7], T[12],
                         T[13], T[14], T[15]);
    atomicAdd(out, (float)(fmin(f1, f2) * (1.0 / P_DIM)));
  }
}

extern "C" void kernel_launch(void* const* d_in, const int* in_sizes, int n_in,
                              void* d_out, int out_size, void* d_ws,
                              size_t ws_size, hipStream_t stream) {
  const float4* z4 = (const float4*)d_in[0];
  const float4* g4 = (const float4*)d_in[1];
  const float* proj = (const float*)d_in[2];
  float* out = (float*)d_out;
  unsigned long long* keys = (unsigned long long*)d_ws;  // 20*2048 u64
  float* sorted = (float*)(keys + 2 * P_DIM * N_ROWS);   // 20*2048 f32

  rc_proj_kernel<<<N_ROWS / 4, 256, 0, stream>>>(z4, g4, proj, keys, out);
  rc_rank_kernel<<<2 * P_DIM * 8, 256, 0, stream>>>((const ulonglong2*)keys,
                                                    sorted);
  rc_stats_kernel<<<P_DIM, 256, 0, stream>>>(sorted, out);
}